// Round 6
// baseline (824.203 us; speedup 1.0000x reference)
//
#include <hip/hip_runtime.h>
#include <hip/hip_fp16.h>
#include <cmath>

// Geometry: (B=2, C=1, Z=128, Y=256, X=256) fp32 in, scalar f32 out
#define NB 2
#define NZ 128
#define NY 256
#define NX 256
#define NPLANE (NY * NX)          // 65536
#define NVOL (NZ * NPLANE)        // 8388608
#define NTOT (NB * NVOL)          // 16777216

#define ZR 6                      // truncated z radius; dropped tail mass ~1e-5
#define C1F 1.0e-4f
#define C2F 9.0e-4f

struct Weights {
    float wz[2 * ZR + 1];         // 13 center taps of normalized 27-tap kernel
    float wy[5];
    float wx[5];
};

// ---------------------------------------------------------------------------
// K1: z-blur of the 5 product fields -> fp16 workspace, packed-fp16 math.
// Block = (32-x strip, y row). Full padded z-column staged as fp16 in LDS
// (140 rows x 32 halfs x 2 imgs = 17.9 KB -> 8 blocks/CU). Thread = (x-octet,
// z): 26 conflict-free ds_read_b128, conv via __hfma2/__hmul2 (no cvt in the
// hot loop), one b128 global store per field (10 stores/thread total).
// ---------------------------------------------------------------------------
__global__ __launch_bounds__(256, 5) void zblur_kernel(const float* __restrict__ A,
                                                       const float* __restrict__ B,
                                                       __half* __restrict__ fields,
                                                       size_t fieldStride,   // CZ*NPLANE halfs
                                                       int b, int zc0, int CZ,
                                                       Weights W)
{
    const int x0 = blockIdx.x * 32;
    const int y  = blockIdx.y;

    __shared__ __half2 As2[140][16];   // row r: z = r-6, zero-padded ends
    __shared__ __half2 Bs2[140][16];

    const size_t basein = (size_t)b * NVOL + (size_t)y * NX + x0;

    // Stage 140 rows x 8 float4 per image (1120 slots), cvt to fp16.
    #pragma unroll
    for (int k = 0; k < 5; ++k) {
        int i = threadIdx.x + k * 256;
        if (i < 1120) {
            int r = i >> 3, c4 = (i & 7) * 4;     // float index 0,4,..,28
            int z = r - ZR;
            float4 va = make_float4(0.f, 0.f, 0.f, 0.f), vb = va;
            if ((unsigned)z < NZ) {
                va = *reinterpret_cast<const float4*>(A + basein + (size_t)z * NPLANE + c4);
                vb = *reinterpret_cast<const float4*>(B + basein + (size_t)z * NPLANE + c4);
            }
            As2[r][c4 >> 1]       = __floats2half2_rn(va.x, va.y);
            As2[r][(c4 >> 1) + 1] = __floats2half2_rn(va.z, va.w);
            Bs2[r][c4 >> 1]       = __floats2half2_rn(vb.x, vb.y);
            Bs2[r][(c4 >> 1) + 1] = __floats2half2_rn(vb.z, vb.w);
        }
    }

    // Broadcast z-weights to packed fp16 (outside the hot loop).
    __half2 wzh[13];
    #pragma unroll
    for (int t = 0; t < 13; ++t) wzh[t] = __float2half2_rn(W.wz[t]);

    __syncthreads();

    const int oct  = threadIdx.x & 3;        // x-octet (8 halfs)
    const int slot = threadIdx.x >> 2;       // 0..63 -> z within slab

    #pragma unroll
    for (int gi = 0; gi < 2; ++gi) {
        if (gi * 64 >= zc0 + CZ || gi * 64 + 64 <= zc0) continue;  // slab outside chunk
        const int z = gi * 64 + slot;        // output z (global)

        const __half2 hz = __float2half2_rn(0.f);
        __half2 acc[5][4];
        #pragma unroll
        for (int f = 0; f < 5; ++f)
            #pragma unroll
            for (int q = 0; q < 4; ++q) acc[f][q] = hz;

        #pragma unroll
        for (int k = 0; k < 13; ++k) {
            int row = z + k;                 // padded row index for tap k
            uint4 ra = *reinterpret_cast<const uint4*>(&As2[row][oct * 4]);
            uint4 rb = *reinterpret_cast<const uint4*>(&Bs2[row][oct * 4]);
            const __half2* ah = reinterpret_cast<const __half2*>(&ra);
            const __half2* bh = reinterpret_cast<const __half2*>(&rb);
            __half2 w = wzh[k];
            #pragma unroll
            for (int q = 0; q < 4; ++q) {
                __half2 a  = ah[q];
                __half2 bb = bh[q];
                acc[0][q] = __hfma2(w, a, acc[0][q]);
                acc[1][q] = __hfma2(w, bb, acc[1][q]);
                acc[2][q] = __hfma2(w, __hmul2(a, a),  acc[2][q]);
                acc[3][q] = __hfma2(w, __hmul2(bb, bb), acc[3][q]);
                acc[4][q] = __hfma2(w, __hmul2(a, bb), acc[4][q]);
            }
        }

        int zr = z - zc0;                    // chunk-relative z
        if (zr >= 0 && zr < CZ) {
            size_t o = (size_t)zr * NPLANE + (size_t)y * NX + x0 + oct * 8;
            #pragma unroll
            for (int f = 0; f < 5; ++f)
                *reinterpret_cast<uint4*>(fields + (size_t)f * fieldStride + o) =
                    *reinterpret_cast<const uint4*>(&acc[f][0]);
        }
    }
}

// ---------------------------------------------------------------------------
// K2: LDS-free fused y-blur + x-blur + SSIM + reduction.
// Thread owns 1 row x 8 x-cols: 5 predicated b128 tap-row loads per field
// (L1/L2 absorbs vertical reuse), fp32 y-blur in regs, x-halo via shfl,
// x-blur + SSIM. Low VGPR -> high occupancy.
// ---------------------------------------------------------------------------
__global__ __launch_bounds__(256, 5) void yx_ssim_kernel(const __half* __restrict__ F,
                                                         size_t fieldStride,
                                                         float* __restrict__ acc_out,
                                                         Weights W)
{
    const int strip = blockIdx.x;             // 32 y-strips of 8 rows
    const int zc    = blockIdx.y;             // chunk-relative plane
    const int tid   = threadIdx.x;
    const int lx    = tid & 31;               // x-subtile 0..31
    const int xs    = lx * 8;
    const int y0    = strip * 8 + (tid >> 5); // this thread's row

    const __half* base = F + (size_t)zc * NPLANE;

    float res[5][8];

    #pragma unroll
    for (int f = 0; f < 5; ++f) {
        const __half* src = base + (size_t)f * fieldStride;

        // 5 tap rows (y0-2 .. y0+2), zero outside image
        uint4 h[5];
        #pragma unroll
        for (int d = 0; d < 5; ++d) {
            int yy = y0 - 2 + d;
            uint4 v = make_uint4(0u, 0u, 0u, 0u);
            if ((unsigned)yy < NY)
                v = *reinterpret_cast<const uint4*>(src + (size_t)yy * NX + xs);
            h[d] = v;
        }

        // y-blur (fp32)
        float T[8];
        #pragma unroll
        for (int j = 0; j < 8; ++j) T[j] = 0.f;
        #pragma unroll
        for (int d = 0; d < 5; ++d) {
            const __half2* ph = reinterpret_cast<const __half2*>(&h[d]);
            float wt = W.wy[d];
            #pragma unroll
            for (int q = 0; q < 4; ++q) {
                float2 u = __half22float2(ph[q]);
                T[2 * q]     = fmaf(wt, u.x, T[2 * q]);
                T[2 * q + 1] = fmaf(wt, u.y, T[2 * q + 1]);
            }
        }

        // x halo from neighbor lanes; zero at image borders
        float sm2 = __shfl_up(T[6], 1, 64);
        float sm1 = __shfl_up(T[7], 1, 64);
        float sp8 = __shfl_down(T[0], 1, 64);
        float sp9 = __shfl_down(T[1], 1, 64);
        float e[12];
        e[0]  = (lx == 0)  ? 0.f : sm2;
        e[1]  = (lx == 0)  ? 0.f : sm1;
        #pragma unroll
        for (int j = 0; j < 8; ++j) e[2 + j] = T[j];
        e[10] = (lx == 31) ? 0.f : sp8;
        e[11] = (lx == 31) ? 0.f : sp9;
        #pragma unroll
        for (int j = 0; j < 8; ++j) {
            float s = 0.f;
            #pragma unroll
            for (int i = 0; i < 5; ++i) s = fmaf(W.wx[i], e[j + i], s);
            res[f][j] = s;
        }
    }

    float local = 0.f;
    #pragma unroll
    for (int j = 0; j < 8; ++j) {
        float mu1 = res[0][j], mu2 = res[1][j];
        float z11 = res[2][j], z22 = res[3][j], z12 = res[4][j];
        float mu1sq = mu1 * mu1, mu2sq = mu2 * mu2, mu12 = mu1 * mu2;
        float num = (2.f * mu12 + C1F) * (2.f * (z12 - mu12) + C2F);
        float den = (mu1sq + mu2sq + C1F) * ((z11 - mu1sq) + (z22 - mu2sq) + C2F);
        local += __fdividef(num, den);
    }

    #pragma unroll
    for (int off = 32; off; off >>= 1)
        local += __shfl_down(local, off, 64);

    __shared__ float wsum[4];
    int lane = tid & 63, wid = tid >> 6;
    if (lane == 0) wsum[wid] = local;
    __syncthreads();
    if (tid == 0)
        atomicAdd(acc_out, wsum[0] + wsum[1] + wsum[2] + wsum[3]);
}

__global__ void zero_kernel(float* p) { *p = 0.f; }

__global__ void finalize_kernel(const float* __restrict__ acc, float* __restrict__ out)
{
    out[0] = 1.0f - acc[0] * (1.0f / (float)NTOT);
}

// ---------------------------------------------------------------------------
extern "C" void kernel_launch(void* const* d_in, const int* in_sizes, int n_in,
                              void* d_out, int out_size, void* d_ws, size_t ws_size,
                              hipStream_t stream)
{
    const float* img1 = (const float*)d_in[0];
    const float* img2 = (const float*)d_in[1];
    float* out = (float*)d_out;

    // ws: [acc pad 64B][5 fp16 fields of CZ*NPLANE]; CZ=128 needs ~84 MB.
    int CZ = 128;
    while (CZ > 32 && 64 + 5ull * CZ * NPLANE * 2ull > ws_size) CZ >>= 1;

    float*  acc    = (float*)d_ws;
    __half* fields = (__half*)((char*)d_ws + 64);
    const size_t fieldStride = (size_t)CZ * NPLANE;

    Weights W;
    {
        double gz[27], sz = 0.0;
        for (int i = 0; i < 27; ++i) { double d = i - 13; gz[i] = exp(-d * d / 4.5); sz += gz[i]; }
        for (int k = -ZR; k <= ZR; ++k) W.wz[k + ZR] = (float)(gz[k + 13] / sz);
        double gy[5], sy = 0.0;
        for (int i = 0; i < 5; ++i) { double d = i - 2; gy[i] = exp(-d * d / 4.5); sy += gy[i]; }
        for (int i = 0; i < 5; ++i) { W.wy[i] = (float)(gy[i] / sy); W.wx[i] = (float)(gy[i] / sy); }
    }

    zero_kernel<<<1, 1, 0, stream>>>(acc);

    for (int b = 0; b < NB; ++b) {
        for (int z0 = 0; z0 < NZ; z0 += CZ) {
            dim3 g1(NX / 32, NY);
            zblur_kernel<<<g1, 256, 0, stream>>>(img1, img2, fields, fieldStride, b, z0, CZ, W);
            dim3 g2(NY / 8, CZ);
            yx_ssim_kernel<<<g2, 256, 0, stream>>>(fields, fieldStride, acc, W);
        }
    }

    finalize_kernel<<<1, 1, 0, stream>>>(acc, out);
}

// Round 7
// 321.028 us; speedup vs baseline: 2.5674x; 2.5674x over previous
//
#include <hip/hip_runtime.h>
#include <hip/hip_fp16.h>
#include <cmath>

// Geometry: (B=2, C=1, Z=128, Y=256, X=256) fp32 in, scalar f32 out
#define NB 2
#define NZ 128
#define NY 256
#define NX 256
#define NPLANE (NY * NX)          // 65536
#define NVOL (NZ * NPLANE)        // 8388608
#define NTOT (NB * NVOL)          // 16777216

#define ZR 6                      // truncated z radius; dropped tail mass ~1e-5
#define C1F 1.0e-4f
#define C2F 9.0e-4f

struct Weights {
    float wz[2 * ZR + 1];         // 13 center taps of normalized 27-tap kernel
    float wy[5];
    float wx[5];
};

// ---------------------------------------------------------------------------
// K1: z-blur of 5 product fields -> fp16 workspace, packed-fp16 math.
// Block = (64-x strip, y row, z-half). LDS: 76 zero-padded planes as fp16
// (19.5 KB -> 8 blocks/CU, grid 2048). Thread = (x-quad, z-group-of-4):
// window-shared conv (16 b64 LDS row-reads -> 4 outputs x 5 fields), stores
// b64 per (z,field) -> 16 lanes make a 128-B contiguous cluster (fixes the
// round-6 8x write amplification).
// ---------------------------------------------------------------------------
__global__ __launch_bounds__(256) void zblur_kernel(const float* __restrict__ A,
                                                    const float* __restrict__ B,
                                                    __half* __restrict__ fields,
                                                    size_t fieldStride,   // CZ*NPLANE halfs
                                                    int b, int zc0, int CZ,
                                                    Weights W)
{
    const int x0 = blockIdx.x * 64;
    const int y  = blockIdx.y;
    const int zb = blockIdx.z * 64;        // z-half base

    __shared__ __half2 As2[76][32];        // row r: z = zb + r - 6, zero-padded
    __shared__ __half2 Bs2[76][32];

    const size_t basein = (size_t)b * NVOL + (size_t)y * NX + x0;

    // Stage 76 rows x 16 float4 per image (1216 slots), cvt to fp16.
    #pragma unroll
    for (int k = 0; k < 5; ++k) {
        int i = threadIdx.x + k * 256;
        if (i < 1216) {
            int r = i >> 4, c4 = (i & 15) << 2;     // float col 0,4,..,60
            int z = zb + r - ZR;
            float4 va = make_float4(0.f, 0.f, 0.f, 0.f), vb = va;
            if ((unsigned)z < NZ) {
                va = *reinterpret_cast<const float4*>(A + basein + (size_t)z * NPLANE + c4);
                vb = *reinterpret_cast<const float4*>(B + basein + (size_t)z * NPLANE + c4);
            }
            As2[r][(c4 >> 1)]     = __floats2half2_rn(va.x, va.y);
            As2[r][(c4 >> 1) + 1] = __floats2half2_rn(va.z, va.w);
            Bs2[r][(c4 >> 1)]     = __floats2half2_rn(vb.x, vb.y);
            Bs2[r][(c4 >> 1) + 1] = __floats2half2_rn(vb.z, vb.w);
        }
    }

    __half2 wzh[13];
    #pragma unroll
    for (int t = 0; t < 13; ++t) wzh[t] = __float2half2_rn(W.wz[t]);

    __syncthreads();

    const int xq = threadIdx.x & 15;       // x-quad: halves xq*4..xq*4+3
    const int zg = threadIdx.x >> 4;       // 0..15 -> local z zg*4..zg*4+3

    const __half2 hz = __float2half2_rn(0.f);
    __half2 acc[4][5][2];
    #pragma unroll
    for (int j = 0; j < 4; ++j)
        #pragma unroll
        for (int f = 0; f < 5; ++f) { acc[j][f][0] = hz; acc[j][f][1] = hz; }

    #pragma unroll
    for (int k = 0; k < 16; ++k) {         // padded rows zg*4 .. zg*4+15
        int row = zg * 4 + k;
        __half2 a0 = As2[row][xq * 2], a1 = As2[row][xq * 2 + 1];
        __half2 b0 = Bs2[row][xq * 2], b1 = Bs2[row][xq * 2 + 1];
        __half2 aa0 = __hmul2(a0, a0), aa1 = __hmul2(a1, a1);
        __half2 bb0 = __hmul2(b0, b0), bb1 = __hmul2(b1, b1);
        __half2 ab0 = __hmul2(a0, b0), ab1 = __hmul2(a1, b1);
        #pragma unroll
        for (int j = 0; j < 4; ++j) {
            const int t = k - j;           // compile-time weight index
            if (t >= 0 && t <= 2 * ZR) {
                __half2 w = wzh[t];
                acc[j][0][0] = __hfma2(w, a0,  acc[j][0][0]);
                acc[j][0][1] = __hfma2(w, a1,  acc[j][0][1]);
                acc[j][1][0] = __hfma2(w, b0,  acc[j][1][0]);
                acc[j][1][1] = __hfma2(w, b1,  acc[j][1][1]);
                acc[j][2][0] = __hfma2(w, aa0, acc[j][2][0]);
                acc[j][2][1] = __hfma2(w, aa1, acc[j][2][1]);
                acc[j][3][0] = __hfma2(w, bb0, acc[j][3][0]);
                acc[j][3][1] = __hfma2(w, bb1, acc[j][3][1]);
                acc[j][4][0] = __hfma2(w, ab0, acc[j][4][0]);
                acc[j][4][1] = __hfma2(w, ab1, acc[j][4][1]);
            }
        }
    }

    #pragma unroll
    for (int j = 0; j < 4; ++j) {
        int z  = zb + zg * 4 + j;
        int zr = z - zc0;                  // chunk-relative z
        if (zr >= 0 && zr < CZ) {
            size_t o = (size_t)zr * NPLANE + (size_t)y * NX + x0 + xq * 4;
            #pragma unroll
            for (int f = 0; f < 5; ++f) {
                uint2 u;
                u.x = *reinterpret_cast<const unsigned*>(&acc[j][f][0]);
                u.y = *reinterpret_cast<const unsigned*>(&acc[j][f][1]);
                *reinterpret_cast<uint2*>(fields + (size_t)f * fieldStride + o) = u;
            }
        }
    }
}

// ---------------------------------------------------------------------------
// K2: fused y-blur + x-blur + SSIM + reduction. Tile = 256x x 8y of one plane.
// Stage ALL 5 fields x 12 rows (halo 2) in one coalesced pass (15 uint2 per
// thread, reg-buffered), 31.7 KB LDS -> 5 blocks/CU, 2 barriers. y-blur from
// LDS (b128), x-halo via shfl (borders zero), SSIM in fp32.
// ---------------------------------------------------------------------------
__global__ __launch_bounds__(256) void yx_ssim_kernel(const __half* __restrict__ F,
                                                      size_t fieldStride,
                                                      float* __restrict__ acc_out,
                                                      Weights W)
{
    const int y0  = blockIdx.x * 8;          // output rows y0..y0+7
    const int zc  = blockIdx.y;              // chunk-relative plane
    const int tid = threadIdx.x;

    __shared__ __align__(16) __half S[5][12][264];   // row r: y = y0-2+r

    const __half* base = F + (size_t)zc * NPLANE;

    // ---- stage: 5 fields x 12 rows x 64 uint2 = 3840 uint2 ----
    uint2 vbuf[15];
    #pragma unroll
    for (int k = 0; k < 15; ++k) {
        int frow = (tid >> 6) + k * 4;       // 0..59
        int f = frow / 12, r = frow - f * 12;
        int yy = y0 - 2 + r;
        int c  = (tid & 63) * 4;             // half col
        uint2 v = make_uint2(0u, 0u);
        if ((unsigned)yy < NY)
            v = *reinterpret_cast<const uint2*>(base + (size_t)f * fieldStride
                                                + (size_t)yy * NX + c);
        vbuf[k] = v;
    }
    #pragma unroll
    for (int k = 0; k < 15; ++k) {
        int frow = (tid >> 6) + k * 4;
        int f = frow / 12, r = frow - f * 12;
        int c = (tid & 63) * 4;
        *reinterpret_cast<uint2*>(&S[f][r][c]) = vbuf[k];
    }
    __syncthreads();

    // ---- y-blur + x-blur + SSIM: thread = (x-octet, output row) ----
    const int oct = tid & 31;
    const int xs  = oct * 8;
    const int row = tid >> 5;                // 0..7

    float res[5][8];
    #pragma unroll
    for (int f = 0; f < 5; ++f) {
        float T[8];
        #pragma unroll
        for (int j = 0; j < 8; ++j) T[j] = 0.f;
        #pragma unroll
        for (int d = 0; d < 5; ++d) {
            uint4 hv = *reinterpret_cast<const uint4*>(&S[f][row + d][xs]);
            const __half2* ph = reinterpret_cast<const __half2*>(&hv);
            float wt = W.wy[d];
            #pragma unroll
            for (int q = 0; q < 4; ++q) {
                float2 u = __half22float2(ph[q]);
                T[2 * q]     = fmaf(wt, u.x, T[2 * q]);
                T[2 * q + 1] = fmaf(wt, u.y, T[2 * q + 1]);
            }
        }

        // x halo from neighbor lanes; zero at image borders
        float sm2 = __shfl_up(T[6], 1, 64);
        float sm1 = __shfl_up(T[7], 1, 64);
        float sp8 = __shfl_down(T[0], 1, 64);
        float sp9 = __shfl_down(T[1], 1, 64);
        float e[12];
        e[0]  = (oct == 0)  ? 0.f : sm2;
        e[1]  = (oct == 0)  ? 0.f : sm1;
        #pragma unroll
        for (int j = 0; j < 8; ++j) e[2 + j] = T[j];
        e[10] = (oct == 31) ? 0.f : sp8;
        e[11] = (oct == 31) ? 0.f : sp9;
        #pragma unroll
        for (int j = 0; j < 8; ++j) {
            float s = 0.f;
            #pragma unroll
            for (int i = 0; i < 5; ++i) s = fmaf(W.wx[i], e[j + i], s);
            res[f][j] = s;
        }
    }

    float local = 0.f;
    #pragma unroll
    for (int j = 0; j < 8; ++j) {
        float mu1 = res[0][j], mu2 = res[1][j];
        float z11 = res[2][j], z22 = res[3][j], z12 = res[4][j];
        float mu1sq = mu1 * mu1, mu2sq = mu2 * mu2, mu12 = mu1 * mu2;
        float num = (2.f * mu12 + C1F) * (2.f * (z12 - mu12) + C2F);
        float den = (mu1sq + mu2sq + C1F) * ((z11 - mu1sq) + (z22 - mu2sq) + C2F);
        local += __fdividef(num, den);
    }

    #pragma unroll
    for (int off = 32; off; off >>= 1)
        local += __shfl_down(local, off, 64);

    __shared__ float wsum[4];
    int lane = tid & 63, wid = tid >> 6;
    if (lane == 0) wsum[wid] = local;
    __syncthreads();
    if (tid == 0)
        atomicAdd(acc_out, wsum[0] + wsum[1] + wsum[2] + wsum[3]);
}

__global__ void zero_kernel(float* p) { *p = 0.f; }

__global__ void finalize_kernel(const float* __restrict__ acc, float* __restrict__ out)
{
    out[0] = 1.0f - acc[0] * (1.0f / (float)NTOT);
}

// ---------------------------------------------------------------------------
extern "C" void kernel_launch(void* const* d_in, const int* in_sizes, int n_in,
                              void* d_out, int out_size, void* d_ws, size_t ws_size,
                              hipStream_t stream)
{
    const float* img1 = (const float*)d_in[0];
    const float* img2 = (const float*)d_in[1];
    float* out = (float*)d_out;

    // ws: [acc pad 64B][5 fp16 fields of CZ*NPLANE]; CZ=128 needs ~84 MB.
    int CZ = 128;
    while (CZ > 32 && 64 + 5ull * CZ * NPLANE * 2ull > ws_size) CZ >>= 1;

    float*  acc    = (float*)d_ws;
    __half* fields = (__half*)((char*)d_ws + 64);
    const size_t fieldStride = (size_t)CZ * NPLANE;

    Weights W;
    {
        double gz[27], sz = 0.0;
        for (int i = 0; i < 27; ++i) { double d = i - 13; gz[i] = exp(-d * d / 4.5); sz += gz[i]; }
        for (int k = -ZR; k <= ZR; ++k) W.wz[k + ZR] = (float)(gz[k + 13] / sz);
        double gy[5], sy = 0.0;
        for (int i = 0; i < 5; ++i) { double d = i - 2; gy[i] = exp(-d * d / 4.5); sy += gy[i]; }
        for (int i = 0; i < 5; ++i) { W.wy[i] = (float)(gy[i] / sy); W.wx[i] = (float)(gy[i] / sy); }
    }

    zero_kernel<<<1, 1, 0, stream>>>(acc);

    for (int b = 0; b < NB; ++b) {
        for (int z0 = 0; z0 < NZ; z0 += CZ) {
            dim3 g1(NX / 64, NY, 2);
            zblur_kernel<<<g1, 256, 0, stream>>>(img1, img2, fields, fieldStride, b, z0, CZ, W);
            dim3 g2(NY / 8, CZ);
            yx_ssim_kernel<<<g2, 256, 0, stream>>>(fields, fieldStride, acc, W);
        }
    }

    finalize_kernel<<<1, 1, 0, stream>>>(acc, out);
}